// Round 2
// baseline (282.905 us; speedup 1.0000x reference)
//
#include <hip/hip_runtime.h>
#include <math.h>

#define C_CLS   64
#define K_SHOTS 512
#define D_DIM   2048
#define BPC     16                        // blocks per class
#define ROWS_PER_BLOCK (K_SHOTS / BPC)    // 32
#define NWAVES  4
#define ROWS_PER_WAVE (ROWS_PER_BLOCK / NWAVES)  // 8
#define NBLK    (C_CLS * BPC)             // 1024 = 4 blocks/CU exactly
#define NF4     8                         // float4 per lane per row (64*8*4 = 2048)

__device__ __forceinline__ float wave_reduce_sum(float v) {
#pragma unroll
    for (int off = 32; off > 0; off >>= 1)
        v += __shfl_xor(v, off, 64);
    return v;
}

// PASS 0: iter 1 — compute squash scale per row, uniform weights (w=1).
// PASS 1: iter 2 — b1 = scale*(z . c1)        (b was 0), store b1.
// PASS 2: iter 3 — b2 = b1 + scale*(z . c2), no store.
// Each pass accumulates unnormalized s = sum_k w_k*scale_k*z_k and sum_k w_k;
// the LAST block per class (device-scope ticket) reduces the 16 partials in a
// FIXED order (deterministic), normalizes, squashes, writes c.
// PASS 1 traverses blocks in REVERSE so the exact-L3-fit input is re-read in
// the order pass 0 cached it (anti-streaming-eviction); PASS 2 forward again.
template <int PASS>
__global__ __launch_bounds__(256, 4)
void route_pass(const float* __restrict__ z,
                float* __restrict__ scale,
                float* __restrict__ bvec,
                const float* __restrict__ c_prev,
                float* __restrict__ c_out,
                float* __restrict__ part_s,
                float* __restrict__ part_e,
                unsigned int* __restrict__ cnt)
{
    __shared__ float4 s_comb[NWAVES][D_DIM / 4];  // 32 KB
    __shared__ float  e_comb[NWAVES];
    __shared__ unsigned int s_ticket;

    const int rawblk = blockIdx.x;
    const int blk  = (PASS == 1) ? (NBLK - 1 - rawblk) : rawblk;
    const int cls  = blk >> 4;          // / BPC
    const int bic  = blk & (BPC - 1);
    const int lane = threadIdx.x & 63;
    const int wid  = threadIdx.x >> 6;
    const int t    = threadIdx.x;

    float4 cp[NF4];
    if (PASS != 0) {
        const float4* cp4 = (const float4*)(c_prev + (size_t)cls * D_DIM);
#pragma unroll
        for (int i = 0; i < NF4; ++i) cp[i] = cp4[lane + i * 64];
    }

    float4 acc[NF4];
#pragma unroll
    for (int i = 0; i < NF4; ++i) acc[i] = make_float4(0.f, 0.f, 0.f, 0.f);
    float esum = 0.f;

    const int k0 = bic * ROWS_PER_BLOCK + wid * ROWS_PER_WAVE;
    const float4* __restrict__ zbase =
        (const float4*)(z + ((size_t)cls * K_SHOTS + k0) * D_DIM);

#pragma unroll 1
    for (int r = 0; r < ROWS_PER_WAVE; ++r) {
        const float4* zr = zbase + (size_t)r * (D_DIM / 4);
        float4 zc[NF4];
#pragma unroll
        for (int i = 0; i < NF4; ++i) zc[i] = zr[lane + i * 64];

        const int k = k0 + r;
        float w, sc;
        if (PASS == 0) {
            float n2 = 0.f;
#pragma unroll
            for (int i = 0; i < NF4; ++i)
                n2 += zc[i].x * zc[i].x + zc[i].y * zc[i].y
                    + zc[i].z * zc[i].z + zc[i].w * zc[i].w;
            n2 = wave_reduce_sum(n2);
            sc = sqrtf(n2) / (1.f + n2);
            if (lane == 0) scale[cls * K_SHOTS + k] = sc;
            w = 1.f;                      // softmax(0): uniform, normalize later
        } else {
            float dot = 0.f;
#pragma unroll
            for (int i = 0; i < NF4; ++i)
                dot += zc[i].x * cp[i].x + zc[i].y * cp[i].y
                     + zc[i].z * cp[i].z + zc[i].w * cp[i].w;
            dot = wave_reduce_sum(dot);
            sc = scale[cls * K_SHOTS + k];
            float bnew = sc * dot;
            if (PASS == 2) bnew += bvec[cls * K_SHOTS + k];
            if (PASS == 1 && lane == 0) bvec[cls * K_SHOTS + k] = bnew;
            w = expf(bnew);               // unnormalized softmax weight
        }
        esum += w;
        const float wsc = w * sc;
#pragma unroll
        for (int i = 0; i < NF4; ++i) {
            acc[i].x += wsc * zc[i].x;
            acc[i].y += wsc * zc[i].y;
            acc[i].z += wsc * zc[i].z;
            acc[i].w += wsc * zc[i].w;
        }
    }

    // deterministic 4-wave combine via LDS, publish block partial
#pragma unroll
    for (int i = 0; i < NF4; ++i) s_comb[wid][lane + i * 64] = acc[i];
    if (lane == 0) e_comb[wid] = esum;
    __syncthreads();

    float4* ps = (float4*)(part_s + (size_t)blk * D_DIM);
#pragma unroll
    for (int j = 0; j < 2; ++j) {
        const int f = t + j * 256;
        const float4 a  = s_comb[0][f];
        const float4 b4 = s_comb[1][f];
        const float4 c4 = s_comb[2][f];
        const float4 d4 = s_comb[3][f];
        float4 s;
        s.x = (a.x + b4.x) + (c4.x + d4.x);
        s.y = (a.y + b4.y) + (c4.y + d4.y);
        s.z = (a.z + b4.z) + (c4.z + d4.z);
        s.w = (a.w + b4.w) + (c4.w + d4.w);
        ps[f] = s;
    }
    if (t == 0) part_e[blk] = (e_comb[0] + e_comb[1]) + (e_comb[2] + e_comb[3]);

    // ticket: barrier drains every wave's stores to L2; the agent-scope
    // acq_rel RMW writes back L2 (release) / invalidates (acquire).
    __syncthreads();
    if (t == 0)
        s_ticket = __hip_atomic_fetch_add(&cnt[cls], 1u,
                                          __ATOMIC_ACQ_REL,
                                          __HIP_MEMORY_SCOPE_AGENT);
    __syncthreads();
    if (s_ticket != BPC - 1) return;

    // === last block of this class: reduce 16 partials (fixed order) ===
    float es = 0.f;
#pragma unroll
    for (int p = 0; p < BPC; ++p) es += part_e[cls * BPC + p];
    const float inv = 1.f / es;

    float4 m[2];
    float n2p = 0.f;
#pragma unroll
    for (int j = 0; j < 2; ++j) {
        const int f = t + j * 256;
        float4 s = make_float4(0.f, 0.f, 0.f, 0.f);
#pragma unroll
        for (int p = 0; p < BPC; ++p) {
            const float4 v =
                ((const float4*)(part_s + (size_t)(cls * BPC + p) * D_DIM))[f];
            s.x += v.x; s.y += v.y; s.z += v.z; s.w += v.w;
        }
        m[j].x = s.x * inv; m[j].y = s.y * inv;
        m[j].z = s.z * inv; m[j].w = s.w * inv;
        n2p += m[j].x * m[j].x + m[j].y * m[j].y
             + m[j].z * m[j].z + m[j].w * m[j].w;
    }
    float n2 = wave_reduce_sum(n2p);
    if (lane == 0) e_comb[wid] = n2;
    __syncthreads();
    n2 = (e_comb[0] + e_comb[1]) + (e_comb[2] + e_comb[3]);
    const float fac = sqrtf(n2) / (1.f + n2);

    float4* co = (float4*)(c_out + (size_t)cls * D_DIM);
#pragma unroll
    for (int j = 0; j < 2; ++j) {
        const int f = t + j * 256;
        float4 o;
        o.x = m[j].x * fac; o.y = m[j].y * fac;
        o.z = m[j].z * fac; o.w = m[j].w * fac;
        co[f] = o;
    }
}

extern "C" void kernel_launch(void* const* d_in, const int* in_sizes, int n_in,
                              void* d_out, int out_size, void* d_ws, size_t ws_size,
                              hipStream_t stream)
{
    const float* z = (const float*)d_in[0];
    float* out = (float*)d_out;
    float* ws  = (float*)d_ws;

    float* scale  = ws;                                   // C*K
    float* bvec   = scale + C_CLS * K_SHOTS;              // C*K
    float* c1     = bvec + C_CLS * K_SHOTS;               // C*D
    float* c2     = c1 + (size_t)C_CLS * D_DIM;           // C*D
    float* part_s = c2 + (size_t)C_CLS * D_DIM;           // NBLK*D
    float* part_e = part_s + (size_t)NBLK * D_DIM;        // NBLK
    unsigned int* cnt = (unsigned int*)(part_e + NBLK);   // 3*C classes
    // total ws: ~9.4 MB

    hipMemsetAsync(cnt, 0, 3 * C_CLS * sizeof(unsigned int), stream);

    route_pass<0><<<NBLK, 256, 0, stream>>>(z, scale, bvec, nullptr, c1,
                                            part_s, part_e, cnt);
    route_pass<1><<<NBLK, 256, 0, stream>>>(z, scale, bvec, c1, c2,
                                            part_s, part_e, cnt + C_CLS);
    route_pass<2><<<NBLK, 256, 0, stream>>>(z, scale, bvec, c2, out,
                                            part_s, part_e, cnt + 2 * C_CLS);
}

// Round 3
// 262.005 us; speedup vs baseline: 1.0798x; 1.0798x over previous
//
#include <hip/hip_runtime.h>
#include <math.h>

#define C_CLS   64
#define K_SHOTS 512
#define D_DIM   2048
#define BPC     16                        // blocks per class
#define ROWS_PER_BLOCK (K_SHOTS / BPC)    // 32
#define NWAVES  4
#define ROWS_PER_WAVE (ROWS_PER_BLOCK / NWAVES)  // 8
#define NBLK    (C_CLS * BPC)             // 1024
#define NF4     8                         // float4 per lane per row (64*8*4 = 2048)

__device__ __forceinline__ float wave_reduce_sum(float v) {
#pragma unroll
    for (int off = 32; off > 0; off >>= 1)
        v += __shfl_xor(v, off, 64);
    return v;
}

// PASS 0: iter 1 — compute squash scale per row, uniform weights (w=1).
// PASS 1: iter 2 — b1 = scale*(z . c1)       (b was 0), store b1.
// PASS 2: iter 3 — b2 = b1 + scale*(z . c2), no store needed.
// Each pass accumulates unnormalized s = sum_k w_k*scale_k*z_k and sum_k w_k;
// the LAST block per class (agent-scope ticket) reduces the 16 partials in a
// FIXED order (deterministic), normalizes by sum(exp), squashes, writes c.
// NOTE: no aggressive launch_bounds — round 2 showed a (256,4) bound caps
// VGPR at 64 and spills the ~128-reg working set to scratch (4x slowdown).
template <int PASS>
__global__ __launch_bounds__(256)
void route_pass(const float* __restrict__ z,
                float* __restrict__ scale,
                float* __restrict__ bvec,
                const float* __restrict__ c_prev,
                float* __restrict__ c_out,
                float* __restrict__ part_s,
                float* __restrict__ part_e,
                unsigned int* __restrict__ cnt)
{
    __shared__ float4 s_comb[NWAVES][D_DIM / 4];  // 32 KB
    __shared__ float  e_comb[NWAVES];
    __shared__ unsigned int s_ticket;

    const int rawblk = blockIdx.x;
    const int blk  = (PASS == 1) ? (NBLK - 1 - rawblk) : rawblk;  // L3-friendly re-walk
    const int cls  = blk >> 4;          // / BPC
    const int bic  = blk & (BPC - 1);
    const int lane = threadIdx.x & 63;
    const int wid  = threadIdx.x >> 6;
    const int t    = threadIdx.x;

    float4 cp[NF4];
    if (PASS != 0) {
        const float4* cp4 = (const float4*)(c_prev + (size_t)cls * D_DIM);
#pragma unroll
        for (int i = 0; i < NF4; ++i) cp[i] = cp4[lane + i * 64];
    }

    float4 acc[NF4];
#pragma unroll
    for (int i = 0; i < NF4; ++i) acc[i] = make_float4(0.f, 0.f, 0.f, 0.f);
    float esum = 0.f;

    const int k0 = bic * ROWS_PER_BLOCK + wid * ROWS_PER_WAVE;
    const float4* __restrict__ zbase =
        (const float4*)(z + ((size_t)cls * K_SHOTS + k0) * D_DIM);

    // explicit double-buffer: load row r+1 while reducing row r
    float4 zcur[NF4];
#pragma unroll
    for (int i = 0; i < NF4; ++i) zcur[i] = zbase[lane + i * 64];

#pragma unroll
    for (int r = 0; r < ROWS_PER_WAVE; ++r) {
        float4 znext[NF4];
        if (r + 1 < ROWS_PER_WAVE) {
            const float4* zn = zbase + (size_t)(r + 1) * (D_DIM / 4);
#pragma unroll
            for (int i = 0; i < NF4; ++i) znext[i] = zn[lane + i * 64];
        }
        const int k = k0 + r;
        float w, sc;
        if (PASS == 0) {
            float n2 = 0.f;
#pragma unroll
            for (int i = 0; i < NF4; ++i)
                n2 += zcur[i].x * zcur[i].x + zcur[i].y * zcur[i].y
                    + zcur[i].z * zcur[i].z + zcur[i].w * zcur[i].w;
            n2 = wave_reduce_sum(n2);
            sc = sqrtf(n2) / (1.f + n2);
            if (lane == 0) scale[cls * K_SHOTS + k] = sc;
            w = 1.f;                      // softmax(0): uniform, normalize later
        } else {
            float dot = 0.f;
#pragma unroll
            for (int i = 0; i < NF4; ++i)
                dot += zcur[i].x * cp[i].x + zcur[i].y * cp[i].y
                     + zcur[i].z * cp[i].z + zcur[i].w * cp[i].w;
            dot = wave_reduce_sum(dot);
            sc = scale[cls * K_SHOTS + k];
            float bnew = sc * dot;
            if (PASS == 2) bnew += bvec[cls * K_SHOTS + k];
            if (PASS == 1 && lane == 0) bvec[cls * K_SHOTS + k] = bnew;
            w = expf(bnew);               // unnormalized softmax weight
        }
        esum += w;
        const float wsc = w * sc;
#pragma unroll
        for (int i = 0; i < NF4; ++i) {
            acc[i].x += wsc * zcur[i].x;
            acc[i].y += wsc * zcur[i].y;
            acc[i].z += wsc * zcur[i].z;
            acc[i].w += wsc * zcur[i].w;
        }
        if (r + 1 < ROWS_PER_WAVE) {
#pragma unroll
            for (int i = 0; i < NF4; ++i) zcur[i] = znext[i];
        }
    }

    // deterministic 4-wave combine via LDS, publish block partial
#pragma unroll
    for (int i = 0; i < NF4; ++i) s_comb[wid][lane + i * 64] = acc[i];
    if (lane == 0) e_comb[wid] = esum;
    __syncthreads();

    float4* ps = (float4*)(part_s + (size_t)blk * D_DIM);
#pragma unroll
    for (int j = 0; j < 2; ++j) {
        const int f = t + j * 256;
        const float4 a  = s_comb[0][f];
        const float4 b4 = s_comb[1][f];
        const float4 c4 = s_comb[2][f];
        const float4 d4 = s_comb[3][f];
        float4 s;
        s.x = (a.x + b4.x) + (c4.x + d4.x);
        s.y = (a.y + b4.y) + (c4.y + d4.y);
        s.z = (a.z + b4.z) + (c4.z + d4.z);
        s.w = (a.w + b4.w) + (c4.w + d4.w);
        ps[f] = s;
    }
    if (t == 0) part_e[blk] = (e_comb[0] + e_comb[1]) + (e_comb[2] + e_comb[3]);

    // ticket: syncthreads orders all this block's stores before the RMW; the
    // agent-scope acq_rel RMW makes them visible device-wide / invalidates
    // stale lines for the reader.
    __syncthreads();
    if (t == 0)
        s_ticket = __hip_atomic_fetch_add(&cnt[cls], 1u,
                                          __ATOMIC_ACQ_REL,
                                          __HIP_MEMORY_SCOPE_AGENT);
    __syncthreads();
    if (s_ticket != BPC - 1) return;

    // === last block of this class: reduce 16 partials (fixed order) ===
    float es = 0.f;
#pragma unroll
    for (int p = 0; p < BPC; ++p) es += part_e[cls * BPC + p];
    const float inv = 1.f / es;

    float4 m[2];
    float n2p = 0.f;
#pragma unroll
    for (int j = 0; j < 2; ++j) {
        const int f = t + j * 256;
        float4 s = make_float4(0.f, 0.f, 0.f, 0.f);
#pragma unroll
        for (int p = 0; p < BPC; ++p) {
            const float4 v =
                ((const float4*)(part_s + (size_t)(cls * BPC + p) * D_DIM))[f];
            s.x += v.x; s.y += v.y; s.z += v.z; s.w += v.w;
        }
        m[j].x = s.x * inv; m[j].y = s.y * inv;
        m[j].z = s.z * inv; m[j].w = s.w * inv;
        n2p += m[j].x * m[j].x + m[j].y * m[j].y
             + m[j].z * m[j].z + m[j].w * m[j].w;
    }
    float n2 = wave_reduce_sum(n2p);
    if (lane == 0) e_comb[wid] = n2;
    __syncthreads();
    n2 = (e_comb[0] + e_comb[1]) + (e_comb[2] + e_comb[3]);
    const float fac = sqrtf(n2) / (1.f + n2);

    float4* co = (float4*)(c_out + (size_t)cls * D_DIM);
#pragma unroll
    for (int j = 0; j < 2; ++j) {
        const int f = t + j * 256;
        float4 o;
        o.x = m[j].x * fac; o.y = m[j].y * fac;
        o.z = m[j].z * fac; o.w = m[j].w * fac;
        co[f] = o;
    }
}

extern "C" void kernel_launch(void* const* d_in, const int* in_sizes, int n_in,
                              void* d_out, int out_size, void* d_ws, size_t ws_size,
                              hipStream_t stream)
{
    const float* z = (const float*)d_in[0];
    float* out = (float*)d_out;
    float* ws  = (float*)d_ws;

    float* scale  = ws;                                   // C*K
    float* bvec   = scale + C_CLS * K_SHOTS;              // C*K
    float* c1     = bvec + C_CLS * K_SHOTS;               // C*D
    float* c2     = c1 + (size_t)C_CLS * D_DIM;           // C*D
    float* part_s = c2 + (size_t)C_CLS * D_DIM;           // NBLK*D
    float* part_e = part_s + (size_t)NBLK * D_DIM;        // NBLK
    unsigned int* cnt = (unsigned int*)(part_e + NBLK);   // 3*C classes
    // total ws: ~9.4 MB

    hipMemsetAsync(cnt, 0, 3 * C_CLS * sizeof(unsigned int), stream);

    route_pass<0><<<NBLK, 256, 0, stream>>>(z, scale, bvec, nullptr, c1,
                                            part_s, part_e, cnt);
    route_pass<1><<<NBLK, 256, 0, stream>>>(z, scale, bvec, c1, c2,
                                            part_s, part_e, cnt + C_CLS);
    route_pass<2><<<NBLK, 256, 0, stream>>>(z, scale, bvec, c2, out,
                                            part_s, part_e, cnt + 2 * C_CLS);
}

// Round 4
// 156.601 us; speedup vs baseline: 1.8065x; 1.6731x over previous
//
#include <hip/hip_runtime.h>
#include <math.h>

#define C_CLS   64
#define K_SHOTS 512
#define D_DIM   2048
#define BPC     16                        // blocks per class
#define ROWS_PER_BLOCK (K_SHOTS / BPC)    // 32
#define NWAVES  4
#define ROWS_PER_WAVE (ROWS_PER_BLOCK / NWAVES)  // 8
#define NBLK    (C_CLS * BPC)             // 1024
#define NF4     8                         // float4 per lane per row (64*8*4 = 2048)

__device__ __forceinline__ float wave_reduce_sum(float v) {
#pragma unroll
    for (int off = 32; off > 0; off >>= 1)
        v += __shfl_xor(v, off, 64);
    return v;
}

// PASS 0: iter 1 — compute squash scale per row, uniform weights (w=1).
// PASS 1: iter 2 — b1 = scale*(z . c1)       (b was 0), store b1.
// PASS 2: iter 3 — b2 = b1 + scale*(z . c2).
// Separate reduce kernel per pass (kernel boundary = free device coherence;
// rounds 2/3 showed per-block agent-scope acq_rel atomics cost ~2x from
// repeated L2 writeback/invalidate).
// L3 trick: z_s is exactly 256 MiB = Infinity Cache size. PASS 1 walks rows
// and blocks in REVERSE (read MRU-first, no LRU thrash-cascade); PASS 2
// forward again. Pure addressing change, no sync semantics.
template <int PASS>
__global__ __launch_bounds__(256)
void route_pass(const float* __restrict__ z,
                float* __restrict__ scale,
                float* __restrict__ bvec,
                const float* __restrict__ c_prev,
                float* __restrict__ part_s,
                float* __restrict__ part_e)
{
    __shared__ float4 s_comb[NWAVES][D_DIM / 4];  // 32 KB
    __shared__ float  e_comb[NWAVES];

    const int rawblk = blockIdx.x;
    const int blk  = (PASS == 1) ? (NBLK - 1 - rawblk) : rawblk;
    const int cls  = blk >> 4;          // / BPC
    const int bic  = blk & (BPC - 1);
    const int lane = threadIdx.x & 63;
    const int wid  = threadIdx.x >> 6;
    const int t    = threadIdx.x;

    float4 cp[NF4];
    if (PASS != 0) {
        const float4* cp4 = (const float4*)(c_prev + (size_t)cls * D_DIM);
#pragma unroll
        for (int i = 0; i < NF4; ++i) cp[i] = cp4[lane + i * 64];
    }

    float4 acc[NF4];
#pragma unroll
    for (int i = 0; i < NF4; ++i) acc[i] = make_float4(0.f, 0.f, 0.f, 0.f);
    float esum = 0.f;

    const int k0 = bic * ROWS_PER_BLOCK + wid * ROWS_PER_WAVE;
    const float4* __restrict__ zbase =
        (const float4*)(z + ((size_t)cls * K_SHOTS + k0) * D_DIM);

    // row visit order: reverse on PASS 1 (MRU-first re-scan of the L3)
    const int r0    = (PASS == 1) ? (ROWS_PER_WAVE - 1) : 0;
    const int rstep = (PASS == 1) ? -1 : 1;

    // explicit double-buffer: load next row while reducing current
    float4 zcur[NF4];
#pragma unroll
    for (int i = 0; i < NF4; ++i) zcur[i] = zbase[(size_t)r0 * (D_DIM / 4) + lane + i * 64];

#pragma unroll
    for (int rr = 0; rr < ROWS_PER_WAVE; ++rr) {
        const int r = r0 + rr * rstep;
        float4 znext[NF4];
        if (rr + 1 < ROWS_PER_WAVE) {
            const float4* zn = zbase + (size_t)(r + rstep) * (D_DIM / 4);
#pragma unroll
            for (int i = 0; i < NF4; ++i) znext[i] = zn[lane + i * 64];
        }
        const int k = k0 + r;
        float w, sc;
        if (PASS == 0) {
            float n2 = 0.f;
#pragma unroll
            for (int i = 0; i < NF4; ++i)
                n2 += zcur[i].x * zcur[i].x + zcur[i].y * zcur[i].y
                    + zcur[i].z * zcur[i].z + zcur[i].w * zcur[i].w;
            n2 = wave_reduce_sum(n2);
            sc = sqrtf(n2) / (1.f + n2);
            if (lane == 0) scale[cls * K_SHOTS + k] = sc;
            w = 1.f;                      // softmax(0): uniform, normalize later
        } else {
            float dot = 0.f;
#pragma unroll
            for (int i = 0; i < NF4; ++i)
                dot += zcur[i].x * cp[i].x + zcur[i].y * cp[i].y
                     + zcur[i].z * cp[i].z + zcur[i].w * cp[i].w;
            dot = wave_reduce_sum(dot);
            sc = scale[cls * K_SHOTS + k];
            float bnew = sc * dot;
            if (PASS == 2) bnew += bvec[cls * K_SHOTS + k];
            if (PASS == 1 && lane == 0) bvec[cls * K_SHOTS + k] = bnew;
            w = expf(bnew);               // unnormalized softmax weight
        }
        esum += w;
        const float wsc = w * sc;
#pragma unroll
        for (int i = 0; i < NF4; ++i) {
            acc[i].x += wsc * zcur[i].x;
            acc[i].y += wsc * zcur[i].y;
            acc[i].z += wsc * zcur[i].z;
            acc[i].w += wsc * zcur[i].w;
        }
        if (rr + 1 < ROWS_PER_WAVE) {
#pragma unroll
            for (int i = 0; i < NF4; ++i) zcur[i] = znext[i];
        }
    }

    // deterministic 4-wave combine via LDS, publish block partial
#pragma unroll
    for (int i = 0; i < NF4; ++i) s_comb[wid][lane + i * 64] = acc[i];
    if (lane == 0) e_comb[wid] = esum;
    __syncthreads();

    float4* ps = (float4*)(part_s + (size_t)blk * D_DIM);
#pragma unroll
    for (int j = 0; j < 2; ++j) {
        const int f = t + j * 256;
        const float4 a  = s_comb[0][f];
        const float4 b4 = s_comb[1][f];
        const float4 c4 = s_comb[2][f];
        const float4 d4 = s_comb[3][f];
        float4 s;
        s.x = (a.x + b4.x) + (c4.x + d4.x);
        s.y = (a.y + b4.y) + (c4.y + d4.y);
        s.z = (a.z + b4.z) + (c4.z + d4.z);
        s.w = (a.w + b4.w) + (c4.w + d4.w);
        ps[f] = s;
    }
    if (t == 0) part_e[blk] = (e_comb[0] + e_comb[1]) + (e_comb[2] + e_comb[3]);
}

// Sum the BPC partials per class (fixed order -> deterministic), normalize by
// sum(exp), squash, write c (or final output).
__global__ __launch_bounds__(256)
void reduce_squash(const float* __restrict__ part_s,
                   const float* __restrict__ part_e,
                   float* __restrict__ c_out)
{
    __shared__ float wred[NWAVES];
    const int cls  = blockIdx.x;
    const int t    = threadIdx.x;
    const int lane = t & 63;
    const int wid  = t >> 6;

    float esum = 0.f;
#pragma unroll
    for (int p = 0; p < BPC; ++p) esum += part_e[cls * BPC + p];
    const float inv = 1.f / esum;

    float4 m[2];
    float n2p = 0.f;
#pragma unroll
    for (int j = 0; j < 2; ++j) {
        const int f = t + j * 256;
        float4 s = make_float4(0.f, 0.f, 0.f, 0.f);
        for (int p = 0; p < BPC; ++p) {
            const float4 v =
                ((const float4*)(part_s + (size_t)(cls * BPC + p) * D_DIM))[f];
            s.x += v.x; s.y += v.y; s.z += v.z; s.w += v.w;
        }
        m[j].x = s.x * inv; m[j].y = s.y * inv;
        m[j].z = s.z * inv; m[j].w = s.w * inv;
        n2p += m[j].x * m[j].x + m[j].y * m[j].y
             + m[j].z * m[j].z + m[j].w * m[j].w;
    }
    float n2 = wave_reduce_sum(n2p);
    if (lane == 0) wred[wid] = n2;
    __syncthreads();
    n2 = (wred[0] + wred[1]) + (wred[2] + wred[3]);
    const float fac = sqrtf(n2) / (1.f + n2);

    float4* co = (float4*)(c_out + (size_t)cls * D_DIM);
#pragma unroll
    for (int j = 0; j < 2; ++j) {
        const int f = t + j * 256;
        float4 o;
        o.x = m[j].x * fac; o.y = m[j].y * fac;
        o.z = m[j].z * fac; o.w = m[j].w * fac;
        co[f] = o;
    }
}

extern "C" void kernel_launch(void* const* d_in, const int* in_sizes, int n_in,
                              void* d_out, int out_size, void* d_ws, size_t ws_size,
                              hipStream_t stream)
{
    const float* z = (const float*)d_in[0];
    float* out = (float*)d_out;
    float* ws  = (float*)d_ws;

    float* scale  = ws;                                   // C*K
    float* bvec   = scale + C_CLS * K_SHOTS;              // C*K
    float* c_buf  = bvec + C_CLS * K_SHOTS;               // C*D
    float* part_s = c_buf + (size_t)C_CLS * D_DIM;        // NBLK*D
    float* part_e = part_s + (size_t)NBLK * D_DIM;        // NBLK
    // total ws: ~8.8 MB

    route_pass<0><<<NBLK, 256, 0, stream>>>(z, scale, bvec, nullptr, part_s, part_e);
    reduce_squash<<<C_CLS, 256, 0, stream>>>(part_s, part_e, c_buf);

    route_pass<1><<<NBLK, 256, 0, stream>>>(z, scale, bvec, c_buf, part_s, part_e);
    reduce_squash<<<C_CLS, 256, 0, stream>>>(part_s, part_e, c_buf);

    route_pass<2><<<NBLK, 256, 0, stream>>>(z, scale, bvec, c_buf, part_s, part_e);
    reduce_squash<<<C_CLS, 256, 0, stream>>>(part_s, part_e, out);
}

// Round 5
// 151.609 us; speedup vs baseline: 1.8660x; 1.0329x over previous
//
#include <hip/hip_runtime.h>
#include <hip/hip_fp16.h>
#include <math.h>

#define C_CLS   64
#define K_SHOTS 512
#define D_DIM   2048
#define BPC     16                        // blocks per class
#define ROWS_PER_BLOCK (K_SHOTS / BPC)    // 32
#define NWAVES  4
#define ROWS_PER_WAVE (ROWS_PER_BLOCK / NWAVES)  // 8
#define NBLK    (C_CLS * BPC)             // 1024
#define NF4     8                         // pass0: float4 chunks/lane/row (fp32)
#define NH4     4                         // pass1/2: float4(=8 half) chunks/lane/row

typedef float v4f __attribute__((ext_vector_type(4)));

// nontemporal fp32 load: keep pass-0's one-shot 256 MiB stream from evicting
// the fp16 z_sq copy we want resident in Infinity Cache for passes 1-2.
__device__ __forceinline__ float4 ntload4(const float* p) {
    v4f v = __builtin_nontemporal_load((const v4f*)p);
    float4 r; r.x = v.x; r.y = v.y; r.z = v.z; r.w = v.w; return r;
}

__device__ __forceinline__ uint2 pack4(float4 v) {
    union { uint2 u; __half2 h[2]; } pk;
    pk.h[0] = __floats2half2_rn(v.x, v.y);
    pk.h[1] = __floats2half2_rn(v.z, v.w);
    return pk.u;
}

__device__ __forceinline__ float wave_reduce_sum(float v) {
#pragma unroll
    for (int off = 32; off > 0; off >>= 1)
        v += __shfl_xor(v, off, 64);
    return v;
}

// Pass 0 (iter 1): read fp32 z (nontemporal), compute per-row squash scale,
// write z_sq = sc*z as fp16 (this is the ONLY fp32 read of z), accumulate
// uniform-weight partial sums.
__global__ __launch_bounds__(256)
void route_pass0(const float* __restrict__ z,
                 __half* __restrict__ z16,
                 float* __restrict__ part_s,
                 float* __restrict__ part_e)
{
    __shared__ float4 s_comb[NWAVES][D_DIM / 4];  // 32 KB
    __shared__ float  e_comb[NWAVES];

    const int blk  = blockIdx.x;
    const int cls  = blk >> 4;
    const int bic  = blk & (BPC - 1);
    const int lane = threadIdx.x & 63;
    const int wid  = threadIdx.x >> 6;
    const int t    = threadIdx.x;

    float4 acc[NF4];
#pragma unroll
    for (int i = 0; i < NF4; ++i) acc[i] = make_float4(0.f, 0.f, 0.f, 0.f);
    float esum = 0.f;

    const int k0 = bic * ROWS_PER_BLOCK + wid * ROWS_PER_WAVE;
    const float* __restrict__ zb = z + ((size_t)cls * K_SHOTS + k0) * D_DIM;

    float4 zcur[NF4];
#pragma unroll
    for (int i = 0; i < NF4; ++i) zcur[i] = ntload4(zb + 4 * (lane + i * 64));

#pragma unroll
    for (int r = 0; r < ROWS_PER_WAVE; ++r) {
        float4 znext[NF4];
        if (r + 1 < ROWS_PER_WAVE) {
            const float* zn = zb + (size_t)(r + 1) * D_DIM;
#pragma unroll
            for (int i = 0; i < NF4; ++i) znext[i] = ntload4(zn + 4 * (lane + i * 64));
        }
        float n2 = 0.f;
#pragma unroll
        for (int i = 0; i < NF4; ++i)
            n2 += zcur[i].x * zcur[i].x + zcur[i].y * zcur[i].y
                + zcur[i].z * zcur[i].z + zcur[i].w * zcur[i].w;
        n2 = wave_reduce_sum(n2);
        const float sc = sqrtf(n2) / (1.f + n2);

        // write fp16 z_sq row (regular store -> cached, want it in L3)
        uint2* p16 = (uint2*)(z16 + ((size_t)cls * K_SHOTS + k0 + r) * D_DIM);
#pragma unroll
        for (int i = 0; i < NF4; ++i) {
            float4 s;
            s.x = sc * zcur[i].x; s.y = sc * zcur[i].y;
            s.z = sc * zcur[i].z; s.w = sc * zcur[i].w;
            p16[lane + i * 64] = pack4(s);
            acc[i].x += s.x; acc[i].y += s.y; acc[i].z += s.z; acc[i].w += s.w;
        }
        esum += 1.f;   // w = 1 (softmax(0) uniform; normalized later)

        if (r + 1 < ROWS_PER_WAVE) {
#pragma unroll
            for (int i = 0; i < NF4; ++i) zcur[i] = znext[i];
        }
    }

    // deterministic 4-wave combine via LDS, publish block partial
#pragma unroll
    for (int i = 0; i < NF4; ++i) s_comb[wid][lane + i * 64] = acc[i];
    if (lane == 0) e_comb[wid] = esum;
    __syncthreads();

    float4* ps = (float4*)(part_s + (size_t)blk * D_DIM);
#pragma unroll
    for (int j = 0; j < 2; ++j) {
        const int f = t + j * 256;
        const float4 a  = s_comb[0][f];
        const float4 b4 = s_comb[1][f];
        const float4 c4 = s_comb[2][f];
        const float4 d4 = s_comb[3][f];
        float4 s;
        s.x = (a.x + b4.x) + (c4.x + d4.x);
        s.y = (a.y + b4.y) + (c4.y + d4.y);
        s.z = (a.z + b4.z) + (c4.z + d4.z);
        s.w = (a.w + b4.w) + (c4.w + d4.w);
        ps[f] = s;
    }
    if (t == 0) part_e[blk] = (e_comb[0] + e_comb[1]) + (e_comb[2] + e_comb[3]);
}

// Passes 1/2 (iters 2/3): read fp16 z_sq (128 MiB, hopefully L3-resident).
// b = dot(z16, c_prev) directly (sc baked in). PASS 1 stores b1 and walks in
// reverse (MRU-first); PASS 2 adds b1 and walks forward.
template <int PASS>
__global__ __launch_bounds__(256)
void route_pass_h(const __half* __restrict__ z16,
                  float* __restrict__ bvec,
                  const float* __restrict__ c_prev,
                  float* __restrict__ part_s,
                  float* __restrict__ part_e)
{
    __shared__ float4 s_comb[NWAVES][D_DIM / 4];  // 32 KB
    __shared__ float  e_comb[NWAVES];

    const int rawblk = blockIdx.x;
    const int blk  = (PASS == 1) ? (NBLK - 1 - rawblk) : rawblk;
    const int cls  = blk >> 4;
    const int bic  = blk & (BPC - 1);
    const int lane = threadIdx.x & 63;
    const int wid  = threadIdx.x >> 6;
    const int t    = threadIdx.x;

    // c_prev fragment: lane covers halfs 8*(lane+j*64)..+7 -> two float4s each
    const float4* cp4 = (const float4*)(c_prev + (size_t)cls * D_DIM);
    float4 cpA[NH4], cpB[NH4];
#pragma unroll
    for (int j = 0; j < NH4; ++j) {
        const int c2i = 2 * (lane + j * 64);
        cpA[j] = cp4[c2i];
        cpB[j] = cp4[c2i + 1];
    }

    float4 acc[2 * NH4];
#pragma unroll
    for (int i = 0; i < 2 * NH4; ++i) acc[i] = make_float4(0.f, 0.f, 0.f, 0.f);
    float esum = 0.f;

    const int k0 = bic * ROWS_PER_BLOCK + wid * ROWS_PER_WAVE;
    const float4* __restrict__ zb =
        (const float4*)(z16 + ((size_t)cls * K_SHOTS + k0) * D_DIM);  // row = D/8 float4s

    const int r0    = (PASS == 1) ? (ROWS_PER_WAVE - 1) : 0;
    const int rstep = (PASS == 1) ? -1 : 1;

    float4 zcur[NH4];
#pragma unroll
    for (int j = 0; j < NH4; ++j)
        zcur[j] = zb[(size_t)r0 * (D_DIM / 8) + lane + j * 64];

#pragma unroll
    for (int rr = 0; rr < ROWS_PER_WAVE; ++rr) {
        const int r = r0 + rr * rstep;
        float4 znext[NH4];
        if (rr + 1 < ROWS_PER_WAVE) {
            const float4* zn = zb + (size_t)(r + rstep) * (D_DIM / 8);
#pragma unroll
            for (int j = 0; j < NH4; ++j) znext[j] = zn[lane + j * 64];
        }

        float dot = 0.f;
#pragma unroll
        for (int j = 0; j < NH4; ++j) {
            const __half2* hp = (const __half2*)&zcur[j];
            const float2 a0 = __half22float2(hp[0]);
            const float2 a1 = __half22float2(hp[1]);
            const float2 a2 = __half22float2(hp[2]);
            const float2 a3 = __half22float2(hp[3]);
            dot += a0.x * cpA[j].x + a0.y * cpA[j].y
                 + a1.x * cpA[j].z + a1.y * cpA[j].w
                 + a2.x * cpB[j].x + a2.y * cpB[j].y
                 + a3.x * cpB[j].z + a3.y * cpB[j].w;
        }
        dot = wave_reduce_sum(dot);

        const int k = k0 + r;
        float bnew = dot;
        if (PASS == 2) bnew += bvec[cls * K_SHOTS + k];
        if (PASS == 1 && lane == 0) bvec[cls * K_SHOTS + k] = bnew;
        const float w = expf(bnew);          // unnormalized softmax weight
        esum += w;

#pragma unroll
        for (int j = 0; j < NH4; ++j) {
            const __half2* hp = (const __half2*)&zcur[j];
            const float2 a0 = __half22float2(hp[0]);
            const float2 a1 = __half22float2(hp[1]);
            const float2 a2 = __half22float2(hp[2]);
            const float2 a3 = __half22float2(hp[3]);
            acc[2 * j].x     += w * a0.x;  acc[2 * j].y     += w * a0.y;
            acc[2 * j].z     += w * a1.x;  acc[2 * j].w     += w * a1.y;
            acc[2 * j + 1].x += w * a2.x;  acc[2 * j + 1].y += w * a2.y;
            acc[2 * j + 1].z += w * a3.x;  acc[2 * j + 1].w += w * a3.y;
        }

        if (rr + 1 < ROWS_PER_WAVE) {
#pragma unroll
            for (int j = 0; j < NH4; ++j) zcur[j] = znext[j];
        }
    }

    // deterministic 4-wave combine via LDS, publish block partial
#pragma unroll
    for (int j = 0; j < NH4; ++j) {
        const int c2i = 2 * (lane + j * 64);
        s_comb[wid][c2i]     = acc[2 * j];
        s_comb[wid][c2i + 1] = acc[2 * j + 1];
    }
    if (lane == 0) e_comb[wid] = esum;
    __syncthreads();

    float4* ps = (float4*)(part_s + (size_t)blk * D_DIM);
#pragma unroll
    for (int j = 0; j < 2; ++j) {
        const int f = t + j * 256;
        const float4 a  = s_comb[0][f];
        const float4 b4 = s_comb[1][f];
        const float4 c4 = s_comb[2][f];
        const float4 d4 = s_comb[3][f];
        float4 s;
        s.x = (a.x + b4.x) + (c4.x + d4.x);
        s.y = (a.y + b4.y) + (c4.y + d4.y);
        s.z = (a.z + b4.z) + (c4.z + d4.z);
        s.w = (a.w + b4.w) + (c4.w + d4.w);
        ps[f] = s;
    }
    if (t == 0) part_e[blk] = (e_comb[0] + e_comb[1]) + (e_comb[2] + e_comb[3]);
}

// Sum the BPC partials per class (fixed order -> deterministic), normalize by
// sum(weights), squash, write c (or final output).
__global__ __launch_bounds__(256)
void reduce_squash(const float* __restrict__ part_s,
                   const float* __restrict__ part_e,
                   float* __restrict__ c_out)
{
    __shared__ float wred[NWAVES];
    const int cls  = blockIdx.x;
    const int t    = threadIdx.x;
    const int lane = t & 63;
    const int wid  = t >> 6;

    float esum = 0.f;
#pragma unroll
    for (int p = 0; p < BPC; ++p) esum += part_e[cls * BPC + p];
    const float inv = 1.f / esum;

    float4 m[2];
    float n2p = 0.f;
#pragma unroll
    for (int j = 0; j < 2; ++j) {
        const int f = t + j * 256;
        float4 s = make_float4(0.f, 0.f, 0.f, 0.f);
        for (int p = 0; p < BPC; ++p) {
            const float4 v =
                ((const float4*)(part_s + (size_t)(cls * BPC + p) * D_DIM))[f];
            s.x += v.x; s.y += v.y; s.z += v.z; s.w += v.w;
        }
        m[j].x = s.x * inv; m[j].y = s.y * inv;
        m[j].z = s.z * inv; m[j].w = s.w * inv;
        n2p += m[j].x * m[j].x + m[j].y * m[j].y
             + m[j].z * m[j].z + m[j].w * m[j].w;
    }
    float n2 = wave_reduce_sum(n2p);
    if (lane == 0) wred[wid] = n2;
    __syncthreads();
    n2 = (wred[0] + wred[1]) + (wred[2] + wred[3]);
    const float fac = sqrtf(n2) / (1.f + n2);

    float4* co = (float4*)(c_out + (size_t)cls * D_DIM);
#pragma unroll
    for (int j = 0; j < 2; ++j) {
        const int f = t + j * 256;
        float4 o;
        o.x = m[j].x * fac; o.y = m[j].y * fac;
        o.z = m[j].z * fac; o.w = m[j].w * fac;
        co[f] = o;
    }
}

extern "C" void kernel_launch(void* const* d_in, const int* in_sizes, int n_in,
                              void* d_out, int out_size, void* d_ws, size_t ws_size,
                              hipStream_t stream)
{
    const float* z = (const float*)d_in[0];
    float* out = (float*)d_out;
    float* ws  = (float*)d_ws;

    float* bvec   = ws;                                   // C*K
    float* c_buf  = bvec + C_CLS * K_SHOTS;               // C*D
    float* part_s = c_buf + (size_t)C_CLS * D_DIM;        // NBLK*D
    float* part_e = part_s + (size_t)NBLK * D_DIM;        // NBLK
    __half* z16   = (__half*)(part_e + NBLK);             // C*K*D halfs (134 MB)
    // total ws: ~143 MB (< poisoned 1 GB)

    route_pass0<<<NBLK, 256, 0, stream>>>(z, z16, part_s, part_e);
    reduce_squash<<<C_CLS, 256, 0, stream>>>(part_s, part_e, c_buf);

    route_pass_h<1><<<NBLK, 256, 0, stream>>>(z16, bvec, c_buf, part_s, part_e);
    reduce_squash<<<C_CLS, 256, 0, stream>>>(part_s, part_e, c_buf);

    route_pass_h<2><<<NBLK, 256, 0, stream>>>(z16, bvec, c_buf, part_s, part_e);
    reduce_squash<<<C_CLS, 256, 0, stream>>>(part_s, part_e, out);
}